// Round 13
// baseline (253.479 us; speedup 1.0000x reference)
//
#include <hip/hip_runtime.h>
#include <hip/hip_bf16.h>

typedef __attribute__((ext_vector_type(8))) short bf16x8;
typedef __attribute__((ext_vector_type(4))) float f32x4;
typedef __attribute__((ext_vector_type(4))) unsigned int u32x4;

#define B_  512
#define N_  256
#define SD_ 1024
#define HD_ 512
#define AD_ 256

__device__ __forceinline__ unsigned short f2bf(float f) {
    unsigned int u = __float_as_uint(f);
    unsigned int r = (u + 0x7FFFu + ((u >> 16) & 1u)) >> 16;
    return (unsigned short)r;
}

__device__ __forceinline__ unsigned int cvtpk(float lo, float hi) {
    unsigned int r;
    asm("v_cvt_pk_bf16_f32 %0, %1, %2" : "=v"(r) : "v"(lo), "v"(hi));
    return r;
}

__device__ __forceinline__ void gload16(const float* g, char* l) {
    __builtin_amdgcn_global_load_lds(
        (const __attribute__((address_space(1))) unsigned int*)g,
        (__attribute__((address_space(3))) unsigned int*)l, 16, 0, 0);
}

// ---------------------------------------------------------------------------
// K0: pack Wh (AD x HD, f32) into bf16 B-fragment layout for 16x16x32 MFMA.
__global__ void k0_pack(const float* __restrict__ Wh, unsigned short* __restrict__ whp) {
    int g = blockIdx.x * 256 + threadIdx.x;
    int ct  = g >> 10;
    int rem = g & 1023;
    int ks  = rem >> 6;
    int l   = rem & 63;
    int a   = ct * 16 + (l & 15);
    int kb  = ks * 32 + (l >> 4) * 8;
    const float* src = Wh + (size_t)a * HD_ + kb;
    float4 v0 = *(const float4*)(src);
    float4 v1 = *(const float4*)(src + 4);
    bf16x8 o;
    o[0] = (short)f2bf(v0.x); o[1] = (short)f2bf(v0.y);
    o[2] = (short)f2bf(v0.z); o[3] = (short)f2bf(v0.w);
    o[4] = (short)f2bf(v1.x); o[5] = (short)f2bf(v1.y);
    o[6] = (short)f2bf(v1.z); o[7] = (short)f2bf(v1.w);
    ((bf16x8*)whp)[g] = o;
}

// ---------------------------------------------------------------------------
// K1: 2 b's per block, 512 threads. sp = state@Ws^T + bs; sn = max(||sp||,eps).
__global__ __launch_bounds__(512) void k1_proj(
    const float* __restrict__ state, const float* __restrict__ Ws,
    const float* __restrict__ bs,
    float* __restrict__ sn, float* __restrict__ spv)
{
    __shared__ float st[2][SD_];
    __shared__ float spl[2][AD_];
    __shared__ float red[2][AD_];
    int tid = threadIdx.x, lane = tid & 63, w = tid >> 6;
    int b0 = blockIdx.x * 2;
    ((float4*)st)[tid] = ((const float4*)(state + (size_t)b0 * SD_))[tid];
    __syncthreads();
    float4 s0[4], s1[4];
    #pragma unroll
    for (int seg = 0; seg < 4; ++seg) {
        s0[seg] = *(const float4*)&st[0][seg * 256 + lane * 4];
        s1[seg] = *(const float4*)&st[1][seg * 256 + lane * 4];
    }
    #pragma unroll 2
    for (int i = 0; i < 32; ++i) {
        int a = w * 32 + i;
        const float4* wr = (const float4*)(Ws + (size_t)a * SD_);
        float p0 = 0.f, p1 = 0.f;
        #pragma unroll
        for (int seg = 0; seg < 4; ++seg) {
            float4 wv = wr[seg * 64 + lane];
            p0 += wv.x * s0[seg].x + wv.y * s0[seg].y + wv.z * s0[seg].z + wv.w * s0[seg].w;
            p1 += wv.x * s1[seg].x + wv.y * s1[seg].y + wv.z * s1[seg].z + wv.w * s1[seg].w;
        }
        #pragma unroll
        for (int d = 1; d < 64; d <<= 1) { p0 += __shfl_xor(p0, d); p1 += __shfl_xor(p1, d); }
        if (lane == 0) {
            float bsa = bs[a];
            spl[0][a] = p0 + bsa;
            spl[1][a] = p1 + bsa;
        }
    }
    __syncthreads();
    int tb = tid >> 8, t = tid & 255;
    float sv = spl[tb][t];
    spv[(size_t)(b0 + tb) * AD_ + t] = sv;
    red[tb][t] = sv * sv;
    __syncthreads();
    for (int s = 128; s > 0; s >>= 1) { if (t < s) red[tb][t] += red[tb][t + s]; __syncthreads(); }
    if (t == 0) sn[b0 + tb] = fmaxf(sqrtf(red[tb][0]), 1e-8f);
}

// ---------------------------------------------------------------------------
// K2a scores, WINDOW-SCHEDULED (R7-R12 all pinned at 1.7 TB/s with 512
// block-private streams; fill kernel's single coherent window gets 6.9 TB/s).
// Block b at step p=(i,kc) stages chunk of row-group g=i*512+b: the 512
// resident blocks read ADJACENT 16KB chunks -> one ~8MB window sweeping
// hints linearly. Scores need no b-locality (k2b gathers via scores array).
// gload_lds (linear dest, pre-swizzled source); bfr loads issued BEFORE the
// stage of c+2 so compiler bfr-waits are vmcnt(4) -> prefetch never drained
// (in-order vmcnt). Raw barrier per phase; spv/bh/sn in LDS (no vm loads
// between phases).
__global__ __launch_bounds__(256, 2) void k2_scores(
    const float* __restrict__ hints, const unsigned short* __restrict__ whp,
    const float* __restrict__ spv, const float* __restrict__ sn,
    const float* __restrict__ bh, float* __restrict__ scores)
{
    __shared__ __align__(16) char smem[59968];
    char* bufs = smem;                        // 3 x 16KB chunk buffers
    float* bh_lds  = (float*)(smem + 49152);  // 256 f32
    float* spv_lds = (float*)(smem + 50176);  // 8 x 256 f32
    float* sn_lds  = (float*)(smem + 58368);  // 8 f32
    float* norm2p  = (float*)(smem + 58432);  // 4 x 32
    float* nump    = (float*)(smem + 58944);  // 4 x 32

    int tid = threadIdx.x, lane = tid & 63, w = tid >> 6;
    int b = blockIdx.x;
    int cl = lane & 15, q = lane >> 4;
    int brow = b >> 3;

    // chunk c: row-group g=(c>>2)*512+b (32 rows), K-slice (c&3)*128..+128.
    // LDS linear e=(row<<5)|pg ; source granule pre-swizzled pg^row (m173).
#define STAGE(c) do {                                                          \
    int gg = ((c) >> 2) * 512 + b;                                             \
    const float* gb = hints + (size_t)gg * (32 * 512) + ((c) & 3) * 128;       \
    char* bp = bufs + ((c) % 3) * 16384;                                       \
    _Pragma("unroll")                                                          \
    for (int j = 0; j < 4; ++j) {                                              \
        int e = j * 256 + tid;                                                 \
        int row = e >> 5, pg = e & 31;                                         \
        gload16(gb + (size_t)row * 512 + ((pg ^ row) << 2), bp + e * 16);      \
    }                                                                          \
} while (0)

    STAGE(0);
    STAGE(1);
    if (tid < 64) ((float4*)bh_lds)[tid] = ((const float4*)bh)[tid];
    #pragma unroll
    for (int i = 0; i < 8; ++i)
        spv_lds[i * 256 + tid] = spv[(size_t)(i * 64 + brow) * 256 + tid];
    if (tid < 8) sn_lds[tid] = sn[tid * 64 + brow];
    __syncthreads();   // one-time full drain: c0,c1 landed, LDS preloads visible

    float bhv[4];
    #pragma unroll
    for (int ci = 0; ci < 4; ++ci) bhv[ci] = bh_lds[(w * 4 + ci) * 16 + cl];

    for (int i = 0; i < 8; ++i) {
        float snb = sn_lds[i];
        float spc[4];
        #pragma unroll
        for (int ci = 0; ci < 4; ++ci)
            spc[ci] = spv_lds[i * 256 + (w * 4 + ci) * 16 + cl];
        f32x4 acc[2][4];
        #pragma unroll
        for (int mf = 0; mf < 2; ++mf)
            #pragma unroll
            for (int ci = 0; ci < 4; ++ci) acc[mf][ci] = (f32x4){0.f, 0.f, 0.f, 0.f};

        #pragma unroll
        for (int kc = 0; kc < 4; ++kc) {
            int c = i * 4 + kc;
            // bfr FIRST (so bfr-waits leave the stage below in flight)
            bf16x8 bfr[16];
            #pragma unroll
            for (int k4 = 0; k4 < 4; ++k4)
                #pragma unroll
                for (int ci = 0; ci < 4; ++ci)
                    bfr[k4 * 4 + ci] = ((const bf16x8*)whp)
                        [((w * 4 + ci) * 16 + kc * 4 + k4) * 64 + lane];
            if (c + 2 < 32) STAGE(c + 2);
            const char* bp = bufs + (c % 3) * 16384;
            #pragma unroll
            for (int k4 = 0; k4 < 4; ++k4) {
                #pragma unroll
                for (int mf = 0; mf < 2; ++mf) {
                    int r = mf * 16 + cl;
                    int lg = k4 * 8 + q * 2;
                    float4 lo = *(const float4*)(bp + r * 512 + ((lg ^ r) << 4));
                    float4 hi = *(const float4*)(bp + r * 512 + (((lg + 1) ^ r) << 4));
                    u32x4 t;
                    t[0] = cvtpk(lo.x, lo.y);
                    t[1] = cvtpk(lo.z, lo.w);
                    t[2] = cvtpk(hi.x, hi.y);
                    t[3] = cvtpk(hi.z, hi.w);
                    bf16x8 afr = __builtin_bit_cast(bf16x8, t);
                    #pragma unroll
                    for (int ci = 0; ci < 4; ++ci)
                        acc[mf][ci] = __builtin_amdgcn_mfma_f32_16x16x32_bf16(
                            afr, bfr[k4 * 4 + ci], acc[mf][ci], 0, 0, 0);
                }
            }
            asm volatile("s_waitcnt lgkmcnt(0)" ::: "memory");
            __builtin_amdgcn_s_barrier();   // raw: vmcnt (stage c+2) stays in flight
        }

        // norm2 + numerator. C layout: col=(w*4+ci)*16+cl, row=mf*16+q*4+rr
        #pragma unroll
        for (int mf = 0; mf < 2; ++mf) {
            #pragma unroll
            for (int rr = 0; rr < 4; ++rr) {
                float vv = 0.f, uu = 0.f;
                #pragma unroll
                for (int ci = 0; ci < 4; ++ci) {
                    float h = acc[mf][ci][rr] + bhv[ci];
                    vv += h * h;
                    uu += spc[ci] * h;
                }
                vv += __shfl_xor(vv, 1); uu += __shfl_xor(uu, 1);
                vv += __shfl_xor(vv, 2); uu += __shfl_xor(uu, 2);
                vv += __shfl_xor(vv, 4); uu += __shfl_xor(uu, 4);
                vv += __shfl_xor(vv, 8); uu += __shfl_xor(uu, 8);
                if (cl == 0) {
                    int idx = w * 32 + mf * 16 + q * 4 + rr;
                    norm2p[idx] = vv;
                    nump[idx]   = uu;
                }
            }
        }
        asm volatile("s_waitcnt lgkmcnt(0)" ::: "memory");
        __builtin_amdgcn_s_barrier();
        if (tid < 32) {
            float n2 = norm2p[tid] + norm2p[32 + tid] + norm2p[64 + tid] + norm2p[96 + tid];
            float nm = nump[tid] + nump[32 + tid] + nump[64 + tid] + nump[96 + tid];
            float hn = fmaxf(sqrtf(n2), 1e-8f);
            scores[(size_t)(i * 512 + b) * 32 + tid] = nm / (snb * hn);
        }
        asm volatile("s_waitcnt lgkmcnt(0)" ::: "memory");
        __builtin_amdgcn_s_barrier();
    }
#undef STAGE
}

// ---------------------------------------------------------------------------
// K2b: per b: softmax over 256 scores, then weighted sum over hints.
__global__ __launch_bounds__(512) void k2b_out(
    const float* __restrict__ hints, const float* __restrict__ scores,
    float* __restrict__ out)
{
    __shared__ float sc[N_];
    __shared__ float red[N_];
    __shared__ float wsm[N_];
    __shared__ float scratch[2048];
    int tid = threadIdx.x;
    int b = blockIdx.x;
    const float* hb = hints + (size_t)b * N_ * HD_;
    if (tid < 256) sc[tid] = scores[(size_t)b * N_ + tid];
    __syncthreads();
    if (tid < 256) red[tid] = sc[tid];
    __syncthreads();
    for (int s = 128; s > 0; s >>= 1) { if (tid < s) red[tid] = fmaxf(red[tid], red[tid + s]); __syncthreads(); }
    float mx = red[0];
    __syncthreads();
    if (tid < 256) { float e = __expf(sc[tid] - mx); sc[tid] = e; red[tid] = e; }
    __syncthreads();
    for (int s = 128; s > 0; s >>= 1) { if (tid < s) red[tid] += red[tid + s]; __syncthreads(); }
    float inv = 1.f / red[0];
    __syncthreads();
    if (tid < 256) wsm[tid] = sc[tid] * inv;
    __syncthreads();

    int hg = tid & 127, ng = tid >> 7;
    const float* hbe = hb + (size_t)(ng * 64) * HD_ + hg * 4;
    float ax = 0.f, ay = 0.f, az = 0.f, aw = 0.f;
    #pragma unroll 8
    for (int n = 0; n < 64; ++n) {
        float4 hv = *(const float4*)(hbe + (size_t)n * HD_);
        float wn = wsm[ng * 64 + n];
        ax += wn * hv.x; ay += wn * hv.y; az += wn * hv.z; aw += wn * hv.w;
    }
    *(float4*)(scratch + ng * 512 + hg * 4) = (float4){ax, ay, az, aw};
    __syncthreads();
    out[(size_t)b * HD_ + tid] =
        scratch[tid] + scratch[512 + tid] + scratch[1024 + tid] + scratch[1536 + tid];
}

// ---------------------------------------------------------------------------
extern "C" void kernel_launch(void* const* d_in, const int* in_sizes, int n_in,
                              void* d_out, int out_size, void* d_ws, size_t ws_size,
                              hipStream_t stream) {
    const float* state = (const float*)d_in[0];
    const float* hints = (const float*)d_in[1];
    const float* Ws    = (const float*)d_in[2];
    const float* bs    = (const float*)d_in[3];
    const float* Wh    = (const float*)d_in[4];
    const float* bh    = (const float*)d_in[5];
    float* out = (float*)d_out;

    float* sn = (float*)d_ws;                              // B
    float* spv = sn + B_;                                  // B*AD
    unsigned short* whp = (unsigned short*)(spv + (size_t)B_ * AD_);  // AD*HD bf16
    float* scores = (float*)(whp + (size_t)AD_ * HD_);     // B*N

    k0_pack<<<64, 256, 0, stream>>>(Wh, whp);
    k1_proj<<<B_ / 2, 512, 0, stream>>>(state, Ws, bs, sn, spv);
    k2_scores<<<B_, 256, 0, stream>>>(hints, whp, spv, sn, bh, scores);
    k2b_out<<<B_, 512, 0, stream>>>(hints, scores, out);
}

// Round 15
// 151.223 us; speedup vs baseline: 1.6762x; 1.6762x over previous
//
#include <hip/hip_runtime.h>
#include <hip/hip_bf16.h>

typedef __attribute__((ext_vector_type(8))) short bf16x8;
typedef __attribute__((ext_vector_type(4))) float f32x4;

#define B_  512
#define N_  256
#define SD_ 1024
#define HD_ 512
#define AD_ 256

__device__ __forceinline__ unsigned short f2bf(float f) {
    unsigned int u = __float_as_uint(f);
    unsigned int r = (u + 0x7FFFu + ((u >> 16) & 1u)) >> 16;
    return (unsigned short)r;
}

// ---------------------------------------------------------------------------
// K0: pack Wh (AD x HD, f32) into bf16 B-fragment layout for 16x16x32 MFMA.
__global__ void k0_pack(const float* __restrict__ Wh, unsigned short* __restrict__ whp) {
    int g = blockIdx.x * 256 + threadIdx.x;
    int ct  = g >> 10;
    int rem = g & 1023;
    int ks  = rem >> 6;
    int l   = rem & 63;
    int a   = ct * 16 + (l & 15);
    int kb  = ks * 32 + (l >> 4) * 8;
    const float* src = Wh + (size_t)a * HD_ + kb;
    float4 v0 = *(const float4*)(src);
    float4 v1 = *(const float4*)(src + 4);
    bf16x8 o;
    o[0] = (short)f2bf(v0.x); o[1] = (short)f2bf(v0.y);
    o[2] = (short)f2bf(v0.z); o[3] = (short)f2bf(v0.w);
    o[4] = (short)f2bf(v1.x); o[5] = (short)f2bf(v1.y);
    o[6] = (short)f2bf(v1.z); o[7] = (short)f2bf(v1.w);
    ((bf16x8*)whp)[g] = o;
}

// ---------------------------------------------------------------------------
// K1: 2 b's per block, 512 threads. sp = state@Ws^T + bs (coalesced Ws reads),
// sn = max(||sp||,eps).
__global__ __launch_bounds__(512) void k1_proj(
    const float* __restrict__ state, const float* __restrict__ Ws,
    const float* __restrict__ bs,
    float* __restrict__ sn, float* __restrict__ spv)
{
    __shared__ float st[2][SD_];
    __shared__ float spl[2][AD_];
    __shared__ float red[2][AD_];
    int tid = threadIdx.x, lane = tid & 63, w = tid >> 6;
    int b0 = blockIdx.x * 2;
    ((float4*)st)[tid] = ((const float4*)(state + (size_t)b0 * SD_))[tid];
    __syncthreads();
    float4 s0[4], s1[4];
    #pragma unroll
    for (int seg = 0; seg < 4; ++seg) {
        s0[seg] = *(const float4*)&st[0][seg * 256 + lane * 4];
        s1[seg] = *(const float4*)&st[1][seg * 256 + lane * 4];
    }
    #pragma unroll 2
    for (int i = 0; i < 32; ++i) {
        int a = w * 32 + i;
        const float4* wr = (const float4*)(Ws + (size_t)a * SD_);
        float p0 = 0.f, p1 = 0.f;
        #pragma unroll
        for (int seg = 0; seg < 4; ++seg) {
            float4 wv = wr[seg * 64 + lane];
            p0 += wv.x * s0[seg].x + wv.y * s0[seg].y + wv.z * s0[seg].z + wv.w * s0[seg].w;
            p1 += wv.x * s1[seg].x + wv.y * s1[seg].y + wv.z * s1[seg].z + wv.w * s1[seg].w;
        }
        #pragma unroll
        for (int d = 1; d < 64; d <<= 1) { p0 += __shfl_xor(p0, d); p1 += __shfl_xor(p1, d); }
        if (lane == 0) {
            float bsa = bs[a];
            spl[0][a] = p0 + bsa;
            spl[1][a] = p1 + bsa;
        }
    }
    __syncthreads();
    int tb = tid >> 8, t = tid & 255;
    float sv = spl[tb][t];
    spv[(size_t)(b0 + tb) * AD_ + t] = sv;
    red[tb][t] = sv * sv;
    __syncthreads();
    for (int s = 128; s > 0; s >>= 1) { if (t < s) red[tb][t] += red[tb][t + s]; __syncthreads(); }
    if (t == 0) sn[b0 + tb] = fmaxf(sqrtf(red[tb][0]), 1e-8f);
}

// ---------------------------------------------------------------------------
// K2 fused (R8-best structure + NT loads): BM=64, BK=128, 16 flat phases,
// depth-2 prefetch, triple-buffer LDS, __syncthreads barriers.
// ONE CHANGE vs R8: hints staging loads are NON-TEMPORAL (L1 no-allocate,
// ext-vector f32x4 type as required by the builtin). Theory: R7-R13 all
// pinned at ~6.8 GB/s/CU read because plain loads allocate in L1 and a 256MB
// stream misses every line -> per-CU L1 fill-path bound. NT loads stream to
// L2 with deeper outstanding capacity. Ws/whp/epilogue loads stay plain.
__device__ __forceinline__ void stage_tile(unsigned short* buf, const f32x4* v,
                                           int rr, int cg) {
    #pragma unroll
    for (int j = 0; j < 4; ++j) {
        int row = j * 16 + rr;
        f32x4 x = v[j];
        ushort4 u;
        u.x = f2bf(x[0]); u.y = f2bf(x[1]); u.z = f2bf(x[2]); u.w = f2bf(x[3]);
        *(ushort4*)((char*)buf + row * 256 + ((cg * 8) ^ ((row & 15) << 4))) = u;
    }
}

__global__ __launch_bounds__(512, 2) void k2_fused(
    const float* __restrict__ hints, const unsigned short* __restrict__ whp,
    const float* __restrict__ spv, const float* __restrict__ sn,
    const float* __restrict__ bh, float* __restrict__ out)
{
    __shared__ __align__(16) char smem[58368];
    unsigned short* buf0 = (unsigned short*)smem;             // 16KB
    unsigned short* buf1 = (unsigned short*)(smem + 16384);   // 16KB
    unsigned short* buf2 = (unsigned short*)(smem + 32768);   // 16KB
    float* sp_lds  = (float*)(smem + 49152);                  // 1KB
    float* bh_lds  = (float*)(smem + 50176);                  // 1KB
    float* norm2p  = (float*)(smem + 51200);                  // 2KB
    float* nump    = (float*)(smem + 53248);                  // 2KB
    float* sc      = (float*)(smem + 55296);                  // 1KB
    float* red     = (float*)(smem + 56320);                  // 1KB
    float* wsm     = (float*)(smem + 57344);                  // 1KB
    float* scratch = (float*)smem;                            // epilogue alias

    int tid = threadIdx.x, lane = tid & 63, w = tid >> 6;
    int b = blockIdx.x;
    const float* hb = hints + (size_t)b * N_ * HD_;
    if (tid < 64) ((float4*)sp_lds)[tid] = ((const float4*)(spv + (size_t)b * AD_))[tid];
    else if (tid < 128) ((float4*)bh_lds)[tid - 64] = ((const float4*)bh)[tid - 64];
    float snb = sn[b];
    int rr = tid >> 5;        // row sub-index (0..15)
    int cg = tid & 31;        // 16B col-group within 128-col chunk
    int cl = lane & 15;
    const float* hrow = hb + (size_t)rr * HD_ + cg * 4;
    __syncthreads();
    float bh0 = bh_lds[(2 * w + 0) * 16 + cl];
    float bh1 = bh_lds[(2 * w + 1) * 16 + cl];
    float sp0 = sp_lds[(2 * w + 0) * 16 + cl];
    float sp1 = sp_lds[(2 * w + 1) * 16 + cl];

    // L[p] address: row block (p>>2)*64 + j*16, col chunk (p&3)*128
#define LADDR(p, j) ((const f32x4*)(hrow + (size_t)(((p) >> 2) * 64 + (j) * 16) * HD_ + ((p) & 3) * 128))

    f32x4 va[4], vb[4];
    #pragma unroll
    for (int j = 0; j < 4; ++j) va[j] = __builtin_nontemporal_load(LADDR(0, j));
    #pragma unroll
    for (int j = 0; j < 4; ++j) vb[j] = __builtin_nontemporal_load(LADDR(1, j));
    stage_tile(buf0, va, rr, cg);
    __syncthreads();
    unsigned short *bufR = buf0, *bufW = buf1, *bufS = buf2;

    for (int mc = 0; mc < 4; ++mc) {
        f32x4 acc[4][2];
        #pragma unroll
        for (int mf = 0; mf < 4; ++mf) {
            acc[mf][0] = (f32x4){0.f, 0.f, 0.f, 0.f};
            acc[mf][1] = (f32x4){0.f, 0.f, 0.f, 0.f};
        }
        #pragma unroll
        for (int kc = 0; kc < 4; ++kc) {
            int p = mc * 4 + kc;
            // A: issue L[p+2] (parity (p+2)&1 == kc&1: even->va, odd->vb)
            if (p + 2 < 16) {
                if ((kc & 1) == 0) {
                    #pragma unroll
                    for (int j = 0; j < 4; ++j) va[j] = __builtin_nontemporal_load(LADDR(p + 2, j));
                } else {
                    #pragma unroll
                    for (int j = 0; j < 4; ++j) vb[j] = __builtin_nontemporal_load(LADDR(p + 2, j));
                }
            }
            // B: MFMA on bufR
            #pragma unroll
            for (int ks = 0; ks < 4; ++ks) {
                bf16x8 bfr0 = ((const bf16x8*)whp)[((2 * w + 0) * 16 + kc * 4 + ks) * 64 + lane];
                bf16x8 bfr1 = ((const bf16x8*)whp)[((2 * w + 1) * 16 + kc * 4 + ks) * 64 + lane];
                #pragma unroll
                for (int mf = 0; mf < 4; ++mf) {
                    int r = mf * 16 + cl;
                    bf16x8 afr = *(const bf16x8*)((const char*)bufR + r * 256 +
                                 ((ks * 64 + (lane >> 4) * 16) ^ ((r & 15) << 4)));
                    acc[mf][0] = __builtin_amdgcn_mfma_f32_16x16x32_bf16(afr, bfr0, acc[mf][0], 0, 0, 0);
                    acc[mf][1] = __builtin_amdgcn_mfma_f32_16x16x32_bf16(afr, bfr1, acc[mf][1], 0, 0, 0);
                }
            }
            // C: stage L[p+1] (parity: kc even -> vb, kc odd -> va)
            if (p + 1 < 16) stage_tile(bufW, (kc & 1) ? va : vb, rr, cg);
            __syncthreads();
            unsigned short* t0 = bufR; bufR = bufW; bufW = bufS; bufS = t0;
        }

        // norm2 + numerator from acc. C layout: col = ct*16+cl, row = mf*16+(lane>>4)*4+r
        #pragma unroll
        for (int mf = 0; mf < 4; ++mf) {
            #pragma unroll
            for (int r = 0; r < 4; ++r) {
                float h0 = acc[mf][0][r] + bh0;
                float h1 = acc[mf][1][r] + bh1;
                float vv = h0 * h0 + h1 * h1;
                float uu = sp0 * h0 + sp1 * h1;
                vv += __shfl_xor(vv, 1); uu += __shfl_xor(uu, 1);
                vv += __shfl_xor(vv, 2); uu += __shfl_xor(uu, 2);
                vv += __shfl_xor(vv, 4); uu += __shfl_xor(uu, 4);
                vv += __shfl_xor(vv, 8); uu += __shfl_xor(uu, 8);
                if (cl == 0) {
                    int idx = w * 64 + mf * 16 + (lane >> 4) * 4 + r;
                    norm2p[idx] = vv;
                    nump[idx]   = uu;
                }
            }
        }
        __syncthreads();
        if (tid < 64) {
            float n2 = 0.f, nm = 0.f;
            #pragma unroll
            for (int ww = 0; ww < 8; ++ww) {
                n2 += norm2p[ww * 64 + tid];
                nm += nump[ww * 64 + tid];
            }
            float hn = fmaxf(sqrtf(n2), 1e-8f);
            sc[mc * 64 + tid] = nm / (snb * hn);
        }
        __syncthreads();
    }
#undef LADDR

    // softmax over sc[256]
    if (tid < 256) red[tid] = sc[tid];
    __syncthreads();
    for (int s = 128; s > 0; s >>= 1) { if (tid < s) red[tid] = fmaxf(red[tid], red[tid + s]); __syncthreads(); }
    float mx = red[0];
    __syncthreads();
    if (tid < 256) { float e = __expf(sc[tid] - mx); sc[tid] = e; red[tid] = e; }
    __syncthreads();
    for (int s = 128; s > 0; s >>= 1) { if (tid < s) red[tid] += red[tid + s]; __syncthreads(); }
    float inv = 1.f / red[0];
    __syncthreads();
    if (tid < 256) wsm[tid] = sc[tid] * inv;
    __syncthreads();

    // weighted sum (vectorized): 4 n-groups x 128 h-groups, then LDS combine
    int hg = tid & 127, ng = tid >> 7;
    const float* hbe = hb + (size_t)(ng * 64) * HD_ + hg * 4;
    float ax = 0.f, ay = 0.f, az = 0.f, aw = 0.f;
    #pragma unroll 8
    for (int n = 0; n < 64; ++n) {
        float4 hv = *(const float4*)(hbe + (size_t)n * HD_);
        float wn = wsm[ng * 64 + n];
        ax += wn * hv.x; ay += wn * hv.y; az += wn * hv.z; aw += wn * hv.w;
    }
    *(float4*)(scratch + ng * 512 + hg * 4) = (float4){ax, ay, az, aw};
    __syncthreads();
    out[(size_t)b * HD_ + tid] =
        scratch[tid] + scratch[512 + tid] + scratch[1024 + tid] + scratch[1536 + tid];
}

// ---------------------------------------------------------------------------
extern "C" void kernel_launch(void* const* d_in, const int* in_sizes, int n_in,
                              void* d_out, int out_size, void* d_ws, size_t ws_size,
                              hipStream_t stream) {
    const float* state = (const float*)d_in[0];
    const float* hints = (const float*)d_in[1];
    const float* Ws    = (const float*)d_in[2];
    const float* bs    = (const float*)d_in[3];
    const float* Wh    = (const float*)d_in[4];
    const float* bh    = (const float*)d_in[5];
    float* out = (float*)d_out;

    float* sn = (float*)d_ws;                              // B
    float* spv = sn + B_;                                  // B*AD
    unsigned short* whp = (unsigned short*)(spv + (size_t)B_ * AD_);  // AD*HD bf16

    k0_pack<<<64, 256, 0, stream>>>(Wh, whp);
    k1_proj<<<B_ / 2, 512, 0, stream>>>(state, Ws, bs, sn, spv);
    k2_fused<<<B_, 512, 0, stream>>>(hints, whp, spv, sn, bh, out);
}